// Round 15
// baseline (126.600 us; speedup 1.0000x reference)
//
#include <hip/hip_runtime.h>
#include <stdint.h>

// Reference: X[256,256,32,32] f32 * mask, mask[b] = concat(ones(51ch),
// bernoulli(fold_in(key(101010), idx[b]), p=0.1, (205,32,32))).
// VERIFIED PRNG (r6/r8/r10-r14 pass, absmax=0): 32-bit partitionable
// threefry: elem i: (b1,b2) = threefry2x32(key, 0, i); word = b1 ^ b2;
//   keep iff word < 429496832u (exact integer form of uniform < 0.1f)
//   key = threefry2x32((0,101010),(0,idx[b]))
// idx layout: DETECTOR REQUIRED (r9 hardcoded-int64 FAILED; detector forms
// all PASSED). Rule: words 0..255; int64 iff all odd words zero.
// Perf ladder: r6 132.3 -> r8 119.1 -> r10-r14 pinned 116-119 regardless of
// MLP/nt/barriers/ILP. r13/r14 PMC: VALU-busy ~102us vs 66us issue floor;
// mem floor ~55-60us (L3 absorbs half the reads, FETCH=131MB).
// Theory: VALU and memory phases serialize because EVERY block is VALU-heavy
// (strided quads mix fixed+mem in all threads).
// r15: CONTIGUOUS quad assignment -> block k owns quads [1024k,1024k+1024)
// (thread quads at +0/+256/+512/+768, still 16B x 64-lane coalesced per
// instruction). Blocks 0-11/example: PURE COPY (no hash, pure mem stream,
// 19% of blocks); block 12 mixed (boundary 13056 = 51*256, 256-aligned ->
// wave-uniform branches); blocks 13-63 pure hash. Dispatcher mixes block
// kinds across CUs -> copy-blocks feed HBM while hash-blocks fill VALU.
// PRNG code byte-identical to r14.

#define EX_STRIDE    262144
#define FIXED_Q      13056

typedef float f32x4 __attribute__((ext_vector_type(4)));

// JAX threefry2x32 (scalar form, for fold_in): 20 rounds, inject every 4.
__device__ __forceinline__ void threefry2x32(uint32_t k0, uint32_t k1,
                                             uint32_t& x0, uint32_t& x1) {
    const uint32_t k2 = k0 ^ k1 ^ 0x1BD11BDAu;
    x0 += k0; x1 += k1;
#define TF_R(r) { x0 += x1; x1 = __builtin_rotateleft32(x1, r); x1 ^= x0; }
    TF_R(13) TF_R(15) TF_R(26) TF_R(6)
    x0 += k1; x1 += k2 + 1u;
    TF_R(17) TF_R(29) TF_R(16) TF_R(24)
    x0 += k2; x1 += k0 + 2u;
    TF_R(13) TF_R(15) TF_R(26) TF_R(6)
    x0 += k0; x1 += k1 + 3u;
    TF_R(17) TF_R(29) TF_R(16) TF_R(24)
    x0 += k1; x1 += k2 + 4u;
    TF_R(13) TF_R(15) TF_R(26) TF_R(6)
    x0 += k2; x1 += k0 + 5u;
#undef TF_R
}

// 4-way lockstep-interleaved threefry for one quad (elements e..e+3).
// Validated r14 (operation-identical to the scalar form; init folds exact).
// Draw: word = x0^x1, keep iff word < 429496832u.
__device__ __forceinline__ void mask_quad4(f32x4& v, uint32_t k0, uint32_t k1,
                                           uint32_t k2, uint32_t e) {
    uint32_t a1 = e + k1;
    uint32_t b1 = a1 + 1u, c1 = a1 + 2u, d1 = a1 + 3u;
    uint32_t a0 = k0 + a1, b0 = k0 + b1, c0 = k0 + c1, d0 = k0 + d1;
    a1 = __builtin_rotateleft32(a1, 13) ^ a0;
    b1 = __builtin_rotateleft32(b1, 13) ^ b0;
    c1 = __builtin_rotateleft32(c1, 13) ^ c0;
    d1 = __builtin_rotateleft32(d1, 13) ^ d0;
#define R4(r) \
    a0 += a1; a1 = __builtin_rotateleft32(a1, r); a1 ^= a0; \
    b0 += b1; b1 = __builtin_rotateleft32(b1, r); b1 ^= b0; \
    c0 += c1; c1 = __builtin_rotateleft32(c1, r); c1 ^= c0; \
    d0 += d1; d1 = __builtin_rotateleft32(d1, r); d1 ^= d0;
#define I4(ka, kb) \
    a0 += (ka); a1 += (kb); b0 += (ka); b1 += (kb); \
    c0 += (ka); c1 += (kb); d0 += (ka); d1 += (kb);
    R4(15) R4(26) R4(6)
    I4(k1, k2 + 1u)
    R4(17) R4(29) R4(16) R4(24)
    I4(k2, k0 + 2u)
    R4(13) R4(15) R4(26) R4(6)
    I4(k0, k1 + 3u)
    R4(17) R4(29) R4(16) R4(24)
    I4(k1, k2 + 4u)
    R4(13) R4(15) R4(26) R4(6)
    I4(k2, k0 + 5u)
#undef R4
#undef I4
    v.x = ((a0 ^ a1) < 429496832u) ? v.x : 0.0f;
    v.y = ((b0 ^ b1) < 429496832u) ? v.y : 0.0f;
    v.z = ((c0 ^ c1) < 429496832u) ? v.z : 0.0f;
    v.w = ((d0 ^ d1) < 429496832u) ? v.w : 0.0f;
}

__global__ __launch_bounds__(256, 4)
void tied_dropout_kernel(const float* __restrict__ X,
                         const int* __restrict__ idx_raw,
                         float* __restrict__ out) {
    const int b = blockIdx.y;
    const int tid = threadIdx.x;
    const int lane = tid & 63;

    // --- barrier-free idx-layout detection (validated r11-r14) ---
    // int64 layout <=> every odd 32-bit word of words 0..255 is zero.
    const int w1 = idx_raw[lane * 4 + 1];
    const int w3 = idx_raw[lane * 4 + 3];
    const unsigned long long ball = __ballot(w1 != 0 || w3 != 0);
    const bool is_i64 = (ball == 0ull);

    // --- fold_in(base_key=(0,101010), idx[b]), SALU via readfirstlane ---
    uint32_t raw_val = (uint32_t)(is_i64 ? idx_raw[2 * b] : idx_raw[b]);
    uint32_t f0 = 0u;
    uint32_t f1 = (uint32_t)__builtin_amdgcn_readfirstlane(raw_val);
    threefry2x32(0u, 101010u, f0, f1);
    const uint32_t k0 = f0, k1 = f1;
    const uint32_t k2 = k0 ^ k1 ^ 0x1BD11BDAu;

    // Contiguous assignment: block owns quads [1024*bx, 1024*bx+1024),
    // thread's quads at q0, q0+256, q0+512, q0+768 (coalesced per inst).
    const int q0 = blockIdx.x * 1024 + tid;

    const size_t ex_off = (size_t)b * EX_STRIDE;
    const f32x4* __restrict__ X4 = reinterpret_cast<const f32x4*>(X + ex_off);
    f32x4* __restrict__ O4 = reinterpret_cast<f32x4*>(out + ex_off);

    f32x4 v0 = X4[q0];
    f32x4 v1 = X4[q0 + 256];
    f32x4 v2 = X4[q0 + 512];
    f32x4 v3 = X4[q0 + 768];

    // Boundary 13056 is 256-aligned -> each branch is wave-uniform.
    // Pure-copy blocks (q0+768 < 13056) skip all hashing entirely.
    if (q0 >= FIXED_Q)
        mask_quad4(v0, k0, k1, k2, (uint32_t)((q0 - FIXED_Q) << 2));
    if (q0 + 256 >= FIXED_Q)
        mask_quad4(v1, k0, k1, k2, (uint32_t)((q0 + 256 - FIXED_Q) << 2));
    if (q0 + 512 >= FIXED_Q)
        mask_quad4(v2, k0, k1, k2, (uint32_t)((q0 + 512 - FIXED_Q) << 2));
    if (q0 + 768 >= FIXED_Q)
        mask_quad4(v3, k0, k1, k2, (uint32_t)((q0 + 768 - FIXED_Q) << 2));

    __builtin_nontemporal_store(v0, O4 + q0);
    __builtin_nontemporal_store(v1, O4 + q0 + 256);
    __builtin_nontemporal_store(v2, O4 + q0 + 512);
    __builtin_nontemporal_store(v3, O4 + q0 + 768);
}

extern "C" void kernel_launch(void* const* d_in, const int* in_sizes, int n_in,
                              void* d_out, int out_size, void* d_ws, size_t ws_size,
                              hipStream_t stream) {
    const float* X = (const float*)d_in[0];
    const int* idx_raw = (const int*)d_in[1];
    // d_in[2] = epoch (ignored; reference applies mask unconditionally)
    float* out = (float*)d_out;

    dim3 block(256, 1, 1);
    dim3 grid(64, 256, 1);                // 64 blocks/example x 256 examples
    tied_dropout_kernel<<<grid, block, 0, stream>>>(X, idx_raw, out);
}

// Round 16
// 121.269 us; speedup vs baseline: 1.0440x; 1.0440x over previous
//
#include <hip/hip_runtime.h>
#include <stdint.h>

// Reference: X[256,256,32,32] f32 * mask, mask[b] = concat(ones(51ch),
// bernoulli(fold_in(key(101010), idx[b]), p=0.1, (205,32,32))).
// VERIFIED PRNG (r6/r8/r10-r15 pass, absmax=0): 32-bit partitionable
// threefry: elem i: (b1,b2) = threefry2x32(key, 0, i); word = b1 ^ b2;
//   keep iff word < 429496832u (exact integer form of uniform < 0.1f)
//   key = threefry2x32((0,101010),(0,idx[b]))
// idx layout: DETECTOR REQUIRED (r9 hardcoded-int64 FAILED; detector forms
// all PASSED). Rule: words 0..255; int64 iff all odd words zero.
// Perf ladder: r6 132.3 -> r8 119.1 -> r10-r14 pinned 116-119 (MLP/nt-loads/
// barriers/ILP all neutral) -> r15 block-specialization REGRESSED 126.6
// (load imbalance: hash blocks became makespan). Best = r14 116.1.
// Model @bench clocks: VALU busy ~71us (61%) vs ~55-65us floor; HBM 403MB
// ~64us floor; both pipes ~60% across 5 schedules.
// r16 single-axis test: r14 byte-identical EXCEPT plain stores (no nt).
// Theory: nt stores bypass L2 and may drain to HBM inefficiently;
// plain stores aggregate in L2 -> full-line bursts (fillBuffer=7TB/s uses
// plain). If neutral -> declare roofline.
// Geometry: stride 262144 = 65536 quads/ex; fixed 13056 quads; quads at
// t, +16384, +32768, +49152; quads 1-3 always mem-region; 13056 = 204*64
// keeps the quad-0 branch wave-uniform.

#define EX_STRIDE    262144
#define FIXED_Q      13056
#define QUART_T      16384

typedef float f32x4 __attribute__((ext_vector_type(4)));

// JAX threefry2x32 (scalar form, for fold_in): 20 rounds, inject every 4.
__device__ __forceinline__ void threefry2x32(uint32_t k0, uint32_t k1,
                                             uint32_t& x0, uint32_t& x1) {
    const uint32_t k2 = k0 ^ k1 ^ 0x1BD11BDAu;
    x0 += k0; x1 += k1;
#define TF_R(r) { x0 += x1; x1 = __builtin_rotateleft32(x1, r); x1 ^= x0; }
    TF_R(13) TF_R(15) TF_R(26) TF_R(6)
    x0 += k1; x1 += k2 + 1u;
    TF_R(17) TF_R(29) TF_R(16) TF_R(24)
    x0 += k2; x1 += k0 + 2u;
    TF_R(13) TF_R(15) TF_R(26) TF_R(6)
    x0 += k0; x1 += k1 + 3u;
    TF_R(17) TF_R(29) TF_R(16) TF_R(24)
    x0 += k1; x1 += k2 + 4u;
    TF_R(13) TF_R(15) TF_R(26) TF_R(6)
    x0 += k2; x1 += k0 + 5u;
#undef TF_R
}

// 4-way lockstep-interleaved threefry for one quad (elements e..e+3).
// Validated r14/r15 (operation-identical to the scalar form; init folds
// exact). Draw: word = x0^x1, keep iff word < 429496832u.
__device__ __forceinline__ void mask_quad4(f32x4& v, uint32_t k0, uint32_t k1,
                                           uint32_t k2, uint32_t e) {
    uint32_t a1 = e + k1;
    uint32_t b1 = a1 + 1u, c1 = a1 + 2u, d1 = a1 + 3u;
    uint32_t a0 = k0 + a1, b0 = k0 + b1, c0 = k0 + c1, d0 = k0 + d1;
    a1 = __builtin_rotateleft32(a1, 13) ^ a0;
    b1 = __builtin_rotateleft32(b1, 13) ^ b0;
    c1 = __builtin_rotateleft32(c1, 13) ^ c0;
    d1 = __builtin_rotateleft32(d1, 13) ^ d0;
#define R4(r) \
    a0 += a1; a1 = __builtin_rotateleft32(a1, r); a1 ^= a0; \
    b0 += b1; b1 = __builtin_rotateleft32(b1, r); b1 ^= b0; \
    c0 += c1; c1 = __builtin_rotateleft32(c1, r); c1 ^= c0; \
    d0 += d1; d1 = __builtin_rotateleft32(d1, r); d1 ^= d0;
#define I4(ka, kb) \
    a0 += (ka); a1 += (kb); b0 += (ka); b1 += (kb); \
    c0 += (ka); c1 += (kb); d0 += (ka); d1 += (kb);
    R4(15) R4(26) R4(6)
    I4(k1, k2 + 1u)
    R4(17) R4(29) R4(16) R4(24)
    I4(k2, k0 + 2u)
    R4(13) R4(15) R4(26) R4(6)
    I4(k0, k1 + 3u)
    R4(17) R4(29) R4(16) R4(24)
    I4(k1, k2 + 4u)
    R4(13) R4(15) R4(26) R4(6)
    I4(k2, k0 + 5u)
#undef R4
#undef I4
    v.x = ((a0 ^ a1) < 429496832u) ? v.x : 0.0f;
    v.y = ((b0 ^ b1) < 429496832u) ? v.y : 0.0f;
    v.z = ((c0 ^ c1) < 429496832u) ? v.z : 0.0f;
    v.w = ((d0 ^ d1) < 429496832u) ? v.w : 0.0f;
}

__global__ __launch_bounds__(256, 4)
void tied_dropout_kernel(const float* __restrict__ X,
                         const int* __restrict__ idx_raw,
                         float* __restrict__ out) {
    const int b = blockIdx.y;
    const int lane = threadIdx.x & 63;

    // --- barrier-free idx-layout detection (validated r11-r15) ---
    // int64 layout <=> every odd 32-bit word of words 0..255 is zero.
    const int w1 = idx_raw[lane * 4 + 1];
    const int w3 = idx_raw[lane * 4 + 3];
    const unsigned long long ball = __ballot(w1 != 0 || w3 != 0);
    const bool is_i64 = (ball == 0ull);

    // --- fold_in(base_key=(0,101010), idx[b]), SALU via readfirstlane ---
    uint32_t raw_val = (uint32_t)(is_i64 ? idx_raw[2 * b] : idx_raw[b]);
    uint32_t f0 = 0u;
    uint32_t f1 = (uint32_t)__builtin_amdgcn_readfirstlane(raw_val);
    threefry2x32(0u, 101010u, f0, f1);
    const uint32_t k0 = f0, k1 = f1;
    const uint32_t k2 = k0 ^ k1 ^ 0x1BD11BDAu;

    const int t = blockIdx.x * blockDim.x + threadIdx.x;   // 0..16383

    const size_t ex_off = (size_t)b * EX_STRIDE;
    const f32x4* __restrict__ X4 = reinterpret_cast<const f32x4*>(X + ex_off);
    f32x4* __restrict__ O4 = reinterpret_cast<f32x4*>(out + ex_off);

    // All 4 loads up front (plain); hash; PLAIN stores (r16 single-axis).
    f32x4 v0 = X4[t];
    f32x4 v1 = X4[t + QUART_T];
    f32x4 v2 = X4[t + 2 * QUART_T];
    f32x4 v3 = X4[t + 3 * QUART_T];

    // Quads 1-3 are always in the mem region (16384 > 13056).
    mask_quad4(v1, k0, k1, k2, (uint32_t)((t + 1 * QUART_T - FIXED_Q) << 2));
    mask_quad4(v2, k0, k1, k2, (uint32_t)((t + 2 * QUART_T - FIXED_Q) << 2));
    mask_quad4(v3, k0, k1, k2, (uint32_t)((t + 3 * QUART_T - FIXED_Q) << 2));

    // Quad 0: fixed channels pass through; mem channels masked (wave-uniform).
    if (t >= FIXED_Q) {
        mask_quad4(v0, k0, k1, k2, (uint32_t)((t - FIXED_Q) << 2));
    }

    O4[t]               = v0;
    O4[t + QUART_T]     = v1;
    O4[t + 2 * QUART_T] = v2;
    O4[t + 3 * QUART_T] = v3;
}

extern "C" void kernel_launch(void* const* d_in, const int* in_sizes, int n_in,
                              void* d_out, int out_size, void* d_ws, size_t ws_size,
                              hipStream_t stream) {
    const float* X = (const float*)d_in[0];
    const int* idx_raw = (const int*)d_in[1];
    // d_in[2] = epoch (ignored; reference applies mask unconditionally)
    float* out = (float*)d_out;

    dim3 block(256, 1, 1);
    dim3 grid(QUART_T / 256, 256, 1);     // (64, B=256)
    tied_dropout_kernel<<<grid, block, 0, stream>>>(X, idx_raw, out);
}

// Round 17
// 112.107 us; speedup vs baseline: 1.1293x; 1.0817x over previous
//
#include <hip/hip_runtime.h>
#include <stdint.h>

// Reference: X[256,256,32,32] f32 * mask, mask[b] = concat(ones(51ch),
// bernoulli(fold_in(key(101010), idx[b]), p=0.1, (205,32,32))).
// VERIFIED PRNG (r6/r8/r10-r16 pass, absmax=0): 32-bit partitionable
// threefry: elem i: (b1,b2) = threefry2x32(key, 0, i); word = b1 ^ b2;
//   keep iff word < 429496832u (exact integer form of uniform < 0.1f)
//   key = threefry2x32((0,101010),(0,idx[b]))
// idx layout: DETECTOR REQUIRED (r9 hardcoded-int64 FAILED; detector forms
// all PASSED). Rule: words 0..255; int64 iff all odd words zero.
// Perf ladder: r6 132.3 (1q) -> r8 119.1 (2q+nt) -> r10 116.9 (4q) ->
// r11 118.6 (ilv stores) -> r12/13 117 (nt-loads off, micro) -> r14 116.1
// (4-way ILP) -> r15 126.6 (block-special REGRESS) -> r16 121.3 (plain
// stores REGRESS: nt stores keep L3 for input; FETCH=131MB = L3 serves
// half the reads). Only consistent lever: work-per-wave (1->2->4 quads).
// r17: 8 quads/thread (32 blocks/example), nt stores restored, all loads
// issued up front, 4-way-ILP hash (validated r14 form).
// Geometry: 65536 quads/ex; thread t in 0..8191 owns quads t + k*8192,
// k=0..7. k=0: all fixed-copy (8191 < 13056). k=1: boundary at t=4864
// (=76*64, wave-uniform). k>=2: all mem-region.

#define EX_STRIDE    262144
#define FIXED_Q      13056
#define OCT_T        8192

typedef float f32x4 __attribute__((ext_vector_type(4)));

// JAX threefry2x32 (scalar form, for fold_in): 20 rounds, inject every 4.
__device__ __forceinline__ void threefry2x32(uint32_t k0, uint32_t k1,
                                             uint32_t& x0, uint32_t& x1) {
    const uint32_t k2 = k0 ^ k1 ^ 0x1BD11BDAu;
    x0 += k0; x1 += k1;
#define TF_R(r) { x0 += x1; x1 = __builtin_rotateleft32(x1, r); x1 ^= x0; }
    TF_R(13) TF_R(15) TF_R(26) TF_R(6)
    x0 += k1; x1 += k2 + 1u;
    TF_R(17) TF_R(29) TF_R(16) TF_R(24)
    x0 += k2; x1 += k0 + 2u;
    TF_R(13) TF_R(15) TF_R(26) TF_R(6)
    x0 += k0; x1 += k1 + 3u;
    TF_R(17) TF_R(29) TF_R(16) TF_R(24)
    x0 += k1; x1 += k2 + 4u;
    TF_R(13) TF_R(15) TF_R(26) TF_R(6)
    x0 += k2; x1 += k0 + 5u;
#undef TF_R
}

// 4-way lockstep-interleaved threefry for one quad (elements e..e+3).
// Validated r14/r15/r16 (operation-identical to the scalar form; init
// folds exact). Draw: word = x0^x1, keep iff word < 429496832u.
__device__ __forceinline__ void mask_quad4(f32x4& v, uint32_t k0, uint32_t k1,
                                           uint32_t k2, uint32_t e) {
    uint32_t a1 = e + k1;
    uint32_t b1 = a1 + 1u, c1 = a1 + 2u, d1 = a1 + 3u;
    uint32_t a0 = k0 + a1, b0 = k0 + b1, c0 = k0 + c1, d0 = k0 + d1;
    a1 = __builtin_rotateleft32(a1, 13) ^ a0;
    b1 = __builtin_rotateleft32(b1, 13) ^ b0;
    c1 = __builtin_rotateleft32(c1, 13) ^ c0;
    d1 = __builtin_rotateleft32(d1, 13) ^ d0;
#define R4(r) \
    a0 += a1; a1 = __builtin_rotateleft32(a1, r); a1 ^= a0; \
    b0 += b1; b1 = __builtin_rotateleft32(b1, r); b1 ^= b0; \
    c0 += c1; c1 = __builtin_rotateleft32(c1, r); c1 ^= c0; \
    d0 += d1; d1 = __builtin_rotateleft32(d1, r); d1 ^= d0;
#define I4(ka, kb) \
    a0 += (ka); a1 += (kb); b0 += (ka); b1 += (kb); \
    c0 += (ka); c1 += (kb); d0 += (ka); d1 += (kb);
    R4(15) R4(26) R4(6)
    I4(k1, k2 + 1u)
    R4(17) R4(29) R4(16) R4(24)
    I4(k2, k0 + 2u)
    R4(13) R4(15) R4(26) R4(6)
    I4(k0, k1 + 3u)
    R4(17) R4(29) R4(16) R4(24)
    I4(k1, k2 + 4u)
    R4(13) R4(15) R4(26) R4(6)
    I4(k2, k0 + 5u)
#undef R4
#undef I4
    v.x = ((a0 ^ a1) < 429496832u) ? v.x : 0.0f;
    v.y = ((b0 ^ b1) < 429496832u) ? v.y : 0.0f;
    v.z = ((c0 ^ c1) < 429496832u) ? v.z : 0.0f;
    v.w = ((d0 ^ d1) < 429496832u) ? v.w : 0.0f;
}

__global__ __launch_bounds__(256, 4)
void tied_dropout_kernel(const float* __restrict__ X,
                         const int* __restrict__ idx_raw,
                         float* __restrict__ out) {
    const int b = blockIdx.y;
    const int lane = threadIdx.x & 63;

    // --- barrier-free idx-layout detection (validated r11-r16) ---
    // int64 layout <=> every odd 32-bit word of words 0..255 is zero.
    const int w1 = idx_raw[lane * 4 + 1];
    const int w3 = idx_raw[lane * 4 + 3];
    const unsigned long long ball = __ballot(w1 != 0 || w3 != 0);
    const bool is_i64 = (ball == 0ull);

    // --- fold_in(base_key=(0,101010), idx[b]), SALU via readfirstlane ---
    uint32_t raw_val = (uint32_t)(is_i64 ? idx_raw[2 * b] : idx_raw[b]);
    uint32_t f0 = 0u;
    uint32_t f1 = (uint32_t)__builtin_amdgcn_readfirstlane(raw_val);
    threefry2x32(0u, 101010u, f0, f1);
    const uint32_t k0 = f0, k1 = f1;
    const uint32_t k2 = k0 ^ k1 ^ 0x1BD11BDAu;

    const int t = blockIdx.x * blockDim.x + threadIdx.x;   // 0..8191

    const size_t ex_off = (size_t)b * EX_STRIDE;
    const f32x4* __restrict__ X4 = reinterpret_cast<const f32x4*>(X + ex_off);
    f32x4* __restrict__ O4 = reinterpret_cast<f32x4*>(out + ex_off);

    // All 8 loads up front (plain: L3-friendly reads); hash; nt stores.
    f32x4 v0 = X4[t];
    f32x4 v1 = X4[t + 1 * OCT_T];
    f32x4 v2 = X4[t + 2 * OCT_T];
    f32x4 v3 = X4[t + 3 * OCT_T];
    f32x4 v4 = X4[t + 4 * OCT_T];
    f32x4 v5 = X4[t + 5 * OCT_T];
    f32x4 v6 = X4[t + 6 * OCT_T];
    f32x4 v7 = X4[t + 7 * OCT_T];

    // k=0 (quads 0..8191): all fixed-copy, no hash.
    // k=1: boundary at t=4864 (wave-uniform: 4864 = 76*64).
    if (t + OCT_T >= FIXED_Q)
        mask_quad4(v1, k0, k1, k2, (uint32_t)((t + 1 * OCT_T - FIXED_Q) << 2));
    mask_quad4(v2, k0, k1, k2, (uint32_t)((t + 2 * OCT_T - FIXED_Q) << 2));
    mask_quad4(v3, k0, k1, k2, (uint32_t)((t + 3 * OCT_T - FIXED_Q) << 2));
    mask_quad4(v4, k0, k1, k2, (uint32_t)((t + 4 * OCT_T - FIXED_Q) << 2));
    mask_quad4(v5, k0, k1, k2, (uint32_t)((t + 5 * OCT_T - FIXED_Q) << 2));
    mask_quad4(v6, k0, k1, k2, (uint32_t)((t + 6 * OCT_T - FIXED_Q) << 2));
    mask_quad4(v7, k0, k1, k2, (uint32_t)((t + 7 * OCT_T - FIXED_Q) << 2));

    __builtin_nontemporal_store(v0, O4 + t);
    __builtin_nontemporal_store(v1, O4 + t + 1 * OCT_T);
    __builtin_nontemporal_store(v2, O4 + t + 2 * OCT_T);
    __builtin_nontemporal_store(v3, O4 + t + 3 * OCT_T);
    __builtin_nontemporal_store(v4, O4 + t + 4 * OCT_T);
    __builtin_nontemporal_store(v5, O4 + t + 5 * OCT_T);
    __builtin_nontemporal_store(v6, O4 + t + 6 * OCT_T);
    __builtin_nontemporal_store(v7, O4 + t + 7 * OCT_T);
}

extern "C" void kernel_launch(void* const* d_in, const int* in_sizes, int n_in,
                              void* d_out, int out_size, void* d_ws, size_t ws_size,
                              hipStream_t stream) {
    const float* X = (const float*)d_in[0];
    const int* idx_raw = (const int*)d_in[1];
    // d_in[2] = epoch (ignored; reference applies mask unconditionally)
    float* out = (float*)d_out;

    dim3 block(256, 1, 1);
    dim3 grid(OCT_T / 256, 256, 1);       // (32, B=256)
    tied_dropout_kernel<<<grid, block, 0, stream>>>(X, idx_raw, out);
}

// Round 18
// 107.773 us; speedup vs baseline: 1.1747x; 1.0402x over previous
//
#include <hip/hip_runtime.h>
#include <stdint.h>

// Reference: X[256,256,32,32] f32 * mask, mask[b] = concat(ones(51ch),
// bernoulli(fold_in(key(101010), idx[b]), p=0.1, (205,32,32))).
// VERIFIED PRNG (r6/r8/r10-r17 pass, absmax=0): 32-bit partitionable
// threefry: elem i: (b1,b2) = threefry2x32(key, 0, i); word = b1 ^ b2;
//   keep iff word < 429496832u (exact integer form of uniform < 0.1f)
//   key = threefry2x32((0,101010),(0,idx[b]))
// idx layout: DETECTOR REQUIRED (r9 hardcoded-int64 FAILED; detector forms
// all PASSED). Rule: words 0..255; int64 iff all odd words zero.
// Perf ladder: r6 132.3 (1q) -> r8 119.1 (2q+nt) -> r10 116.9 (4q) ->
// r14 116.1 (ILP) -> r17 112.1 (8q). Regressions: r11 ilv-stores, r15
// block-special (imbalance), r16 plain-stores (nt stores preserve L3 for
// input; FETCH=131MB = L3 serves half the reads). ONLY working lever:
// work-per-wave amortization (preamble+drain over longer hash bursts).
// r18: 16 quads/thread (16 blocks/example, 16384 waves total).
// Geometry: 65536 quads/ex; thread t in 0..4095 owns quads t + k*4096,
// k=0..15. k=0-2: all fixed-copy (max 12287 < 13056). k=3: boundary at
// t=768 (=12*64, wave-uniform). k>=4: all mem-region.

#define EX_STRIDE    262144
#define FIXED_Q      13056
#define SIXT_T       4096

typedef float f32x4 __attribute__((ext_vector_type(4)));

// JAX threefry2x32 (scalar form, for fold_in): 20 rounds, inject every 4.
__device__ __forceinline__ void threefry2x32(uint32_t k0, uint32_t k1,
                                             uint32_t& x0, uint32_t& x1) {
    const uint32_t k2 = k0 ^ k1 ^ 0x1BD11BDAu;
    x0 += k0; x1 += k1;
#define TF_R(r) { x0 += x1; x1 = __builtin_rotateleft32(x1, r); x1 ^= x0; }
    TF_R(13) TF_R(15) TF_R(26) TF_R(6)
    x0 += k1; x1 += k2 + 1u;
    TF_R(17) TF_R(29) TF_R(16) TF_R(24)
    x0 += k2; x1 += k0 + 2u;
    TF_R(13) TF_R(15) TF_R(26) TF_R(6)
    x0 += k0; x1 += k1 + 3u;
    TF_R(17) TF_R(29) TF_R(16) TF_R(24)
    x0 += k1; x1 += k2 + 4u;
    TF_R(13) TF_R(15) TF_R(26) TF_R(6)
    x0 += k2; x1 += k0 + 5u;
#undef TF_R
}

// 4-way lockstep-interleaved threefry for one quad (elements e..e+3).
// Validated r14-r17 (operation-identical to the scalar form; init folds
// exact). Draw: word = x0^x1, keep iff word < 429496832u.
__device__ __forceinline__ void mask_quad4(f32x4& v, uint32_t k0, uint32_t k1,
                                           uint32_t k2, uint32_t e) {
    uint32_t a1 = e + k1;
    uint32_t b1 = a1 + 1u, c1 = a1 + 2u, d1 = a1 + 3u;
    uint32_t a0 = k0 + a1, b0 = k0 + b1, c0 = k0 + c1, d0 = k0 + d1;
    a1 = __builtin_rotateleft32(a1, 13) ^ a0;
    b1 = __builtin_rotateleft32(b1, 13) ^ b0;
    c1 = __builtin_rotateleft32(c1, 13) ^ c0;
    d1 = __builtin_rotateleft32(d1, 13) ^ d0;
#define R4(r) \
    a0 += a1; a1 = __builtin_rotateleft32(a1, r); a1 ^= a0; \
    b0 += b1; b1 = __builtin_rotateleft32(b1, r); b1 ^= b0; \
    c0 += c1; c1 = __builtin_rotateleft32(c1, r); c1 ^= c0; \
    d0 += d1; d1 = __builtin_rotateleft32(d1, r); d1 ^= d0;
#define I4(ka, kb) \
    a0 += (ka); a1 += (kb); b0 += (ka); b1 += (kb); \
    c0 += (ka); c1 += (kb); d0 += (ka); d1 += (kb);
    R4(15) R4(26) R4(6)
    I4(k1, k2 + 1u)
    R4(17) R4(29) R4(16) R4(24)
    I4(k2, k0 + 2u)
    R4(13) R4(15) R4(26) R4(6)
    I4(k0, k1 + 3u)
    R4(17) R4(29) R4(16) R4(24)
    I4(k1, k2 + 4u)
    R4(13) R4(15) R4(26) R4(6)
    I4(k2, k0 + 5u)
#undef R4
#undef I4
    v.x = ((a0 ^ a1) < 429496832u) ? v.x : 0.0f;
    v.y = ((b0 ^ b1) < 429496832u) ? v.y : 0.0f;
    v.z = ((c0 ^ c1) < 429496832u) ? v.z : 0.0f;
    v.w = ((d0 ^ d1) < 429496832u) ? v.w : 0.0f;
}

__global__ __launch_bounds__(256, 4)
void tied_dropout_kernel(const float* __restrict__ X,
                         const int* __restrict__ idx_raw,
                         float* __restrict__ out) {
    const int b = blockIdx.y;
    const int lane = threadIdx.x & 63;

    // --- barrier-free idx-layout detection (validated r11-r17) ---
    // int64 layout <=> every odd 32-bit word of words 0..255 is zero.
    const int w1 = idx_raw[lane * 4 + 1];
    const int w3 = idx_raw[lane * 4 + 3];
    const unsigned long long ball = __ballot(w1 != 0 || w3 != 0);
    const bool is_i64 = (ball == 0ull);

    // --- fold_in(base_key=(0,101010), idx[b]), SALU via readfirstlane ---
    uint32_t raw_val = (uint32_t)(is_i64 ? idx_raw[2 * b] : idx_raw[b]);
    uint32_t f0 = 0u;
    uint32_t f1 = (uint32_t)__builtin_amdgcn_readfirstlane(raw_val);
    threefry2x32(0u, 101010u, f0, f1);
    const uint32_t k0 = f0, k1 = f1;
    const uint32_t k2 = k0 ^ k1 ^ 0x1BD11BDAu;

    const int t = blockIdx.x * blockDim.x + threadIdx.x;   // 0..4095

    const size_t ex_off = (size_t)b * EX_STRIDE;
    const f32x4* __restrict__ X4 = reinterpret_cast<const f32x4*>(X + ex_off);
    f32x4* __restrict__ O4 = reinterpret_cast<f32x4*>(out + ex_off);

    // All 16 loads up front (plain: L3-friendly reads); hash; nt stores.
    f32x4 v0  = X4[t];
    f32x4 v1  = X4[t + 1 * SIXT_T];
    f32x4 v2  = X4[t + 2 * SIXT_T];
    f32x4 v3  = X4[t + 3 * SIXT_T];
    f32x4 v4  = X4[t + 4 * SIXT_T];
    f32x4 v5  = X4[t + 5 * SIXT_T];
    f32x4 v6  = X4[t + 6 * SIXT_T];
    f32x4 v7  = X4[t + 7 * SIXT_T];
    f32x4 v8  = X4[t + 8 * SIXT_T];
    f32x4 v9  = X4[t + 9 * SIXT_T];
    f32x4 v10 = X4[t + 10 * SIXT_T];
    f32x4 v11 = X4[t + 11 * SIXT_T];
    f32x4 v12 = X4[t + 12 * SIXT_T];
    f32x4 v13 = X4[t + 13 * SIXT_T];
    f32x4 v14 = X4[t + 14 * SIXT_T];
    f32x4 v15 = X4[t + 15 * SIXT_T];

    // k=0..2: all fixed-copy (no hash). k=3: boundary at t=768 (wave-
    // uniform). k>=4: all mem-region.
    if (t + 3 * SIXT_T >= FIXED_Q)
        mask_quad4(v3, k0, k1, k2, (uint32_t)((t + 3 * SIXT_T - FIXED_Q) << 2));
    mask_quad4(v4,  k0, k1, k2, (uint32_t)((t + 4 * SIXT_T - FIXED_Q) << 2));
    mask_quad4(v5,  k0, k1, k2, (uint32_t)((t + 5 * SIXT_T - FIXED_Q) << 2));
    mask_quad4(v6,  k0, k1, k2, (uint32_t)((t + 6 * SIXT_T - FIXED_Q) << 2));
    mask_quad4(v7,  k0, k1, k2, (uint32_t)((t + 7 * SIXT_T - FIXED_Q) << 2));
    mask_quad4(v8,  k0, k1, k2, (uint32_t)((t + 8 * SIXT_T - FIXED_Q) << 2));
    mask_quad4(v9,  k0, k1, k2, (uint32_t)((t + 9 * SIXT_T - FIXED_Q) << 2));
    mask_quad4(v10, k0, k1, k2, (uint32_t)((t + 10 * SIXT_T - FIXED_Q) << 2));
    mask_quad4(v11, k0, k1, k2, (uint32_t)((t + 11 * SIXT_T - FIXED_Q) << 2));
    mask_quad4(v12, k0, k1, k2, (uint32_t)((t + 12 * SIXT_T - FIXED_Q) << 2));
    mask_quad4(v13, k0, k1, k2, (uint32_t)((t + 13 * SIXT_T - FIXED_Q) << 2));
    mask_quad4(v14, k0, k1, k2, (uint32_t)((t + 14 * SIXT_T - FIXED_Q) << 2));
    mask_quad4(v15, k0, k1, k2, (uint32_t)((t + 15 * SIXT_T - FIXED_Q) << 2));

    __builtin_nontemporal_store(v0,  O4 + t);
    __builtin_nontemporal_store(v1,  O4 + t + 1 * SIXT_T);
    __builtin_nontemporal_store(v2,  O4 + t + 2 * SIXT_T);
    __builtin_nontemporal_store(v3,  O4 + t + 3 * SIXT_T);
    __builtin_nontemporal_store(v4,  O4 + t + 4 * SIXT_T);
    __builtin_nontemporal_store(v5,  O4 + t + 5 * SIXT_T);
    __builtin_nontemporal_store(v6,  O4 + t + 6 * SIXT_T);
    __builtin_nontemporal_store(v7,  O4 + t + 7 * SIXT_T);
    __builtin_nontemporal_store(v8,  O4 + t + 8 * SIXT_T);
    __builtin_nontemporal_store(v9,  O4 + t + 9 * SIXT_T);
    __builtin_nontemporal_store(v10, O4 + t + 10 * SIXT_T);
    __builtin_nontemporal_store(v11, O4 + t + 11 * SIXT_T);
    __builtin_nontemporal_store(v12, O4 + t + 12 * SIXT_T);
    __builtin_nontemporal_store(v13, O4 + t + 13 * SIXT_T);
    __builtin_nontemporal_store(v14, O4 + t + 14 * SIXT_T);
    __builtin_nontemporal_store(v15, O4 + t + 15 * SIXT_T);
}

extern "C" void kernel_launch(void* const* d_in, const int* in_sizes, int n_in,
                              void* d_out, int out_size, void* d_ws, size_t ws_size,
                              hipStream_t stream) {
    const float* X = (const float*)d_in[0];
    const int* idx_raw = (const int*)d_in[1];
    // d_in[2] = epoch (ignored; reference applies mask unconditionally)
    float* out = (float*)d_out;

    dim3 block(256, 1, 1);
    dim3 grid(SIXT_T / 256, 256, 1);      // (16, B=256)
    tied_dropout_kernel<<<grid, block, 0, stream>>>(X, idx_raw, out);
}